// Round 1
// baseline (349.758 us; speedup 1.0000x reference)
//
#include <hip/hip_runtime.h>
#include <hip/hip_bf16.h>

#define B_ 2
#define S_ 2048
#define D_ 768
#define E_ 8
#define F_ 3072
#define NT (B_*S_)            // 4096 tokens

typedef __attribute__((ext_vector_type(8))) short bf16x8;   // 8 bf16 (4 VGPRs)
typedef __attribute__((ext_vector_type(4))) float f32x4;
typedef __attribute__((ext_vector_type(8))) unsigned short u16x8;

__device__ __forceinline__ unsigned short f2bf(float f){
  __hip_bfloat16 h = __float2bfloat16(f);
  return *reinterpret_cast<unsigned short*>(&h);
}

__device__ __forceinline__ void gll16(const void* g, void* l){
  __builtin_amdgcn_global_load_lds((const __attribute__((address_space(1))) unsigned int*)g,
                                   (__attribute__((address_space(3))) unsigned int*)l,
                                   16, 0, 0);
}

// ---------------------------------------------------------------------------
// Router: fp32 logits (exact-ish), softmax, first-max argmax, bucket build,
// x -> bf16 conversion. One wave per token.
// ---------------------------------------------------------------------------
__global__ __launch_bounds__(256) void router_kernel(
    const float* __restrict__ x, const float* __restrict__ wr,
    float* __restrict__ logits_out, float* __restrict__ idx_out,
    float* __restrict__ probs, int* __restrict__ counts,
    int* __restrict__ bucket, unsigned short* __restrict__ xbf)
{
  const int wave = threadIdx.x >> 6, lane = threadIdx.x & 63;
  const int token = blockIdx.x * 4 + wave;
  const float* xp = x + (size_t)token * D_;

  float acc[E_] = {0.f,0.f,0.f,0.f,0.f,0.f,0.f,0.f};
  float xv[12];
  #pragma unroll
  for (int i = 0; i < 12; ++i){
    const int d = lane + i*64;
    const float v = xp[d];
    xv[i] = v;
    const float4 w0 = *(const float4*)(wr + d*8);
    const float4 w1 = *(const float4*)(wr + d*8 + 4);
    acc[0] += v*w0.x; acc[1] += v*w0.y; acc[2] += v*w0.z; acc[3] += v*w0.w;
    acc[4] += v*w1.x; acc[5] += v*w1.y; acc[6] += v*w1.z; acc[7] += v*w1.w;
  }
  #pragma unroll
  for (int j = 0; j < E_; ++j){
    float a = acc[j];
    for (int off = 32; off > 0; off >>= 1) a += __shfl_xor(a, off);
    acc[j] = a;
  }
  // bf16 copy of x (A-operand for GEMM1)
  #pragma unroll
  for (int i = 0; i < 12; ++i){
    const int d = lane + i*64;
    xbf[(size_t)token * D_ + d] = f2bf(xv[i]);
  }
  if (lane == 0){
    float m = acc[0];
    #pragma unroll
    for (int j = 1; j < E_; ++j) m = fmaxf(m, acc[j]);
    float p[E_]; float s = 0.f;
    #pragma unroll
    for (int j = 0; j < E_; ++j){ p[j] = expf(acc[j] - m); s += p[j]; }
    const float inv = 1.0f / s;
    int best = 0; float bp = p[0]*inv;
    #pragma unroll
    for (int j = 1; j < E_; ++j){ const float pj = p[j]*inv; if (pj > bp){ bp = pj; best = j; } }
    float* lo = logits_out + (size_t)token * E_;
    #pragma unroll
    for (int j = 0; j < E_; ++j) lo[j] = acc[j];
    idx_out[token] = (float)best;
    probs[token] = bp;
    const int pos = atomicAdd(&counts[best], 1);
    bucket[best * NT + pos] = token;
  }
}

// ---------------------------------------------------------------------------
// Transpose + fp32->bf16: in [E][R][C] f32 -> out [E][C][R] bf16
// grid: (C/64, R/64, E), 256 threads, 64x64 tile via LDS
// ---------------------------------------------------------------------------
__global__ __launch_bounds__(256) void transpose_cvt(
    const float* __restrict__ in, unsigned short* __restrict__ outp, int R, int C)
{
  __shared__ float tile[64][65];
  const int e = blockIdx.z;
  const int r0 = blockIdx.y << 6, c0 = blockIdx.x << 6;
  const float* src = in + (size_t)e * R * C;
  unsigned short* dst = outp + (size_t)e * R * C;
  const int tid = threadIdx.x;
  {
    const int lr = tid >> 4, lc = (tid & 15) << 2;
    #pragma unroll
    for (int rr = 0; rr < 4; ++rr){
      const int row = (rr << 4) + lr;
      const float4 v = *(const float4*)(src + (size_t)(r0 + row) * C + c0 + lc);
      tile[row][lc+0] = v.x; tile[row][lc+1] = v.y;
      tile[row][lc+2] = v.z; tile[row][lc+3] = v.w;
    }
  }
  __syncthreads();
  {
    const int wr = tid >> 3, wc = (tid & 7) << 3;
    #pragma unroll
    for (int it = 0; it < 2; ++it){
      const int crow = (it << 5) + wr;
      u16x8 o;
      #pragma unroll
      for (int j = 0; j < 8; ++j) o[j] = f2bf(tile[wc + j][crow]);
      *(u16x8*)(dst + (size_t)(c0 + crow) * R + r0 + wc) = o;
    }
  }
}

// ---------------------------------------------------------------------------
// Grouped GEMM: C[rows of expert e][NCOLS] = A(gathered rows)[K] x Bt[NCOLS][K]
// tile 64(M) x 128(N) x 64(K-step); 256 threads = 4 waves, wave tile 64x32.
// A,B staged to LDS via global_load_lds w=16, inverse-XOR-swizzled source.
// RELU=true: out = relu -> bf16 h1. RELU=false: out = prob * acc -> fp32.
// grid: (NCOLS/128, 64, E)
// ---------------------------------------------------------------------------
template<int K, int NCOLS, bool RELU>
__global__ __launch_bounds__(256) void gemm_grouped(
    const unsigned short* __restrict__ Ab, const unsigned short* __restrict__ Bt,
    const int* __restrict__ counts, const int* __restrict__ bucket,
    const float* __restrict__ probs, unsigned short* __restrict__ h1out,
    float* __restrict__ fout)
{
  __shared__ unsigned short As[64*64];    // 64 rows x 128B (swizzled)
  __shared__ unsigned short Bs[128*64];   // 128 rows x 128B (swizzled)
  const int e = blockIdx.z, mt = blockIdx.y, nt = blockIdx.x;
  const int cnt = counts[e];
  if ((mt << 6) >= cnt) return;
  const int fbase = nt << 7;
  const int tid = threadIdx.x, wave = tid >> 6, lane = tid & 63;
  const int* bkt = bucket + e * NT;

  // ---- staging addresses (pre-swizzled global source, linear LDS dest) ----
  const int inrow = (lane & 7) << 4;           // byte offset in 128B row
  const int rsub  = lane >> 3;                 // 0..7: row within 8-row chunk
  const int rowA0 = (wave << 4) + rsub;
  const int rowA1 = rowA0 + 8;
  const int cm1 = cnt - 1;
  int gA0 = (mt << 6) + rowA0; if (gA0 > cm1) gA0 = cm1;
  int gA1 = (mt << 6) + rowA1; if (gA1 > cm1) gA1 = cm1;
  const int t0 = bkt[gA0], t1 = bkt[gA1];
  const char* pA0 = (const char*)Ab + (size_t)t0 * (K*2) + (inrow ^ ((rowA0 & 7) << 4));
  const char* pA1 = (const char*)Ab + (size_t)t1 * (K*2) + (inrow ^ ((rowA1 & 7) << 4));
  char* lA0 = (char*)As + (wave << 11);
  char* lA1 = lA0 + 1024;

  const char* pB[4];
  char* lB[4];
  #pragma unroll
  for (int c = 0; c < 4; ++c){
    const int rowB = (wave << 5) + (c << 3) + rsub;
    pB[c] = (const char*)Bt + (size_t)(e * NCOLS + fbase + rowB) * (K*2)
            + (inrow ^ ((rowB & 7) << 4));
    lB[c] = (char*)Bs + (wave << 12) + (c << 10);
  }

  f32x4 acc[4][2] = {};
  const char* AsB = (const char*)As;
  const char* BsB = (const char*)Bs;
  const int lo16 = lane & 15;
  const int hi = lane >> 4;

  for (int kt = 0; kt < K/64; ++kt){
    const int off = kt << 7;                  // 64 bf16 = 128 B per K-step
    gll16(pA0 + off, lA0);
    gll16(pA1 + off, lA1);
    gll16(pB[0] + off, lB[0]);
    gll16(pB[1] + off, lB[1]);
    gll16(pB[2] + off, lB[2]);
    gll16(pB[3] + off, lB[3]);
    __syncthreads();
    #pragma unroll
    for (int kf = 0; kf < 2; ++kf){
      const int ko = (kf << 6) + (hi << 4);   // byte offset of 8 K-elems
      bf16x8 af[4], bfr[2];
      #pragma unroll
      for (int mf = 0; mf < 4; ++mf){
        const int row = (mf << 4) + lo16;
        af[mf] = *(const bf16x8*)(AsB + row*128 + (ko ^ ((row & 7) << 4)));
      }
      #pragma unroll
      for (int nf = 0; nf < 2; ++nf){
        const int col = (wave << 5) + (nf << 4) + lo16;
        bfr[nf] = *(const bf16x8*)(BsB + col*128 + (ko ^ ((col & 7) << 4)));
      }
      #pragma unroll
      for (int mf = 0; mf < 4; ++mf)
        #pragma unroll
        for (int nf = 0; nf < 2; ++nf)
          acc[mf][nf] = __builtin_amdgcn_mfma_f32_16x16x32_bf16(af[mf], bfr[nf], acc[mf][nf], 0, 0, 0);
    }
    __syncthreads();
  }

  // ---- epilogue ----
  const int rem = cnt - (mt << 6);
  #pragma unroll
  for (int mf = 0; mf < 4; ++mf){
    #pragma unroll
    for (int j = 0; j < 4; ++j){
      const int r = (mf << 4) + (hi << 2) + j;
      if (r < rem){
        const int tok = bkt[(mt << 6) + r];
        if constexpr (RELU){
          #pragma unroll
          for (int nf = 0; nf < 2; ++nf){
            float v = acc[mf][nf][j];
            v = v > 0.f ? v : 0.f;
            h1out[(size_t)tok * NCOLS + fbase + (wave << 5) + (nf << 4) + lo16] = f2bf(v);
          }
        } else {
          const float p = probs[tok];
          #pragma unroll
          for (int nf = 0; nf < 2; ++nf)
            fout[(size_t)tok * NCOLS + fbase + (wave << 5) + (nf << 4) + lo16] = p * acc[mf][nf][j];
        }
      }
    }
  }
}

// ---------------------------------------------------------------------------
extern "C" void kernel_launch(void* const* d_in, const int* in_sizes, int n_in,
                              void* d_out, int out_size, void* d_ws, size_t ws_size,
                              hipStream_t stream)
{
  const float* x  = (const float*)d_in[0];   // [2,2048,768]
  const float* wr = (const float*)d_in[1];   // [768,8]
  const float* w1 = (const float*)d_in[2];   // [8,768,3072]
  const float* w2 = (const float*)d_in[3];   // [8,3072,768]
  float* out = (float*)d_out;

  constexpr size_t OUT_L = (size_t)NT * D_;          // router_logits offset
  constexpr size_t OUT_I = OUT_L + (size_t)NT * E_;  // expert_index offset

  char* ws = (char*)d_ws;
  int*            counts = (int*)ws;                          // 32 B
  float*          probs  = (float*)(ws + 1024);               // 16 KB
  int*            bucket = (int*)(ws + (32u << 10));          // 128 KB
  unsigned short* xbf    = (unsigned short*)(ws + (256u << 10));  // 6 MB
  unsigned short* w1t    = (unsigned short*)(ws + (8ull  << 20)); // 36 MB [E][F][D]
  unsigned short* w2t    = (unsigned short*)(ws + (48ull << 20)); // 36 MB [E][D][F]
  unsigned short* h1     = (unsigned short*)(ws + (88ull << 20)); // 24 MB [NT][F]

  hipMemsetAsync(counts, 0, E_ * sizeof(int), stream);

  router_kernel<<<dim3(NT/4), dim3(256), 0, stream>>>(
      x, wr, out + OUT_L, out + OUT_I, probs, counts, bucket, xbf);

  transpose_cvt<<<dim3(F_/64, D_/64, E_), dim3(256), 0, stream>>>(w1, w1t, D_, F_);
  transpose_cvt<<<dim3(D_/64, F_/64, E_), dim3(256), 0, stream>>>(w2, w2t, F_, D_);

  gemm_grouped<D_, F_, true><<<dim3(F_/128, 64, E_), dim3(256), 0, stream>>>(
      xbf, w1t, counts, bucket, nullptr, h1, nullptr);

  gemm_grouped<F_, D_, false><<<dim3(D_/128, 64, E_), dim3(256), 0, stream>>>(
      h1, w2t, counts, bucket, probs, nullptr, out);
}

// Round 2
// 339.843 us; speedup vs baseline: 1.0292x; 1.0292x over previous
//
#include <hip/hip_runtime.h>
#include <hip/hip_bf16.h>

#define B_ 2
#define S_ 2048
#define D_ 768
#define E_ 8
#define F_ 3072
#define NT (B_*S_)            // 4096 tokens
#define BM 128
#define MAXTILES 40           // sum_e ceil(cnt_e/128) <= 32 + 8

typedef __attribute__((ext_vector_type(8))) short bf16x8;   // 8 bf16 (4 VGPRs)
typedef __attribute__((ext_vector_type(4))) float f32x4;
typedef __attribute__((ext_vector_type(8))) unsigned short u16x8;

__device__ __forceinline__ unsigned short f2bf(float f){
  __hip_bfloat16 h = __float2bfloat16(f);
  return *reinterpret_cast<unsigned short*>(&h);
}

__device__ __forceinline__ void gll16(const void* g, void* l){
  __builtin_amdgcn_global_load_lds((const __attribute__((address_space(1))) unsigned int*)g,
                                   (__attribute__((address_space(3))) unsigned int*)l,
                                   16, 0, 0);
}

// ---------------------------------------------------------------------------
// Router: fp32 logits, softmax, first-max argmax, bucket build, x -> bf16.
// ---------------------------------------------------------------------------
__global__ __launch_bounds__(256) void router_kernel(
    const float* __restrict__ x, const float* __restrict__ wr,
    float* __restrict__ logits_out, float* __restrict__ idx_out,
    float* __restrict__ probs, int* __restrict__ counts,
    int* __restrict__ bucket, unsigned short* __restrict__ xbf)
{
  const int wave = threadIdx.x >> 6, lane = threadIdx.x & 63;
  const int token = blockIdx.x * 4 + wave;
  const float* xp = x + (size_t)token * D_;

  float acc[E_] = {0.f,0.f,0.f,0.f,0.f,0.f,0.f,0.f};
  float xv[12];
  #pragma unroll
  for (int i = 0; i < 12; ++i){
    const int d = lane + i*64;
    const float v = xp[d];
    xv[i] = v;
    const float4 w0 = *(const float4*)(wr + d*8);
    const float4 w1 = *(const float4*)(wr + d*8 + 4);
    acc[0] += v*w0.x; acc[1] += v*w0.y; acc[2] += v*w0.z; acc[3] += v*w0.w;
    acc[4] += v*w1.x; acc[5] += v*w1.y; acc[6] += v*w1.z; acc[7] += v*w1.w;
  }
  #pragma unroll
  for (int j = 0; j < E_; ++j){
    float a = acc[j];
    for (int off = 32; off > 0; off >>= 1) a += __shfl_xor(a, off);
    acc[j] = a;
  }
  #pragma unroll
  for (int i = 0; i < 12; ++i){
    const int d = lane + i*64;
    xbf[(size_t)token * D_ + d] = f2bf(xv[i]);
  }
  if (lane == 0){
    float m = acc[0];
    #pragma unroll
    for (int j = 1; j < E_; ++j) m = fmaxf(m, acc[j]);
    float p[E_]; float s = 0.f;
    #pragma unroll
    for (int j = 0; j < E_; ++j){ p[j] = expf(acc[j] - m); s += p[j]; }
    const float inv = 1.0f / s;
    int best = 0; float bp = p[0]*inv;
    #pragma unroll
    for (int j = 1; j < E_; ++j){ const float pj = p[j]*inv; if (pj > bp){ bp = pj; best = j; } }
    float* lo = logits_out + (size_t)token * E_;
    #pragma unroll
    for (int j = 0; j < E_; ++j) lo[j] = acc[j];
    idx_out[token] = (float)best;
    probs[token] = bp;
    const int pos = atomicAdd(&counts[best], 1);
    bucket[best * NT + pos] = token;
  }
}

// ---------------------------------------------------------------------------
// Tile map: meta[0]=ntiles, meta[1+e]=compact offset, meta[16+i]=(e<<16)|mt
// ---------------------------------------------------------------------------
__global__ void build_tiles(const int* __restrict__ counts, int* __restrict__ meta)
{
  if (threadIdx.x == 0 && blockIdx.x == 0){
    int off = 0, n = 0;
    for (int e = 0; e < E_; ++e){
      const int c = counts[e];
      meta[1+e] = off;
      const int t = (c + BM - 1) / BM;
      for (int m = 0; m < t; ++m){ meta[16 + n] = (e << 16) | m; ++n; }
      off += c;
    }
    meta[0] = n;
  }
}

// ---------------------------------------------------------------------------
// Transpose + fp32->bf16: in [E][R][C] f32 -> out [E][C][R] bf16
// ---------------------------------------------------------------------------
__global__ __launch_bounds__(256) void transpose_cvt(
    const float* __restrict__ in, unsigned short* __restrict__ outp, int R, int C)
{
  __shared__ float tile[64][65];
  const int e = blockIdx.z;
  const int r0 = blockIdx.y << 6, c0 = blockIdx.x << 6;
  const float* src = in + (size_t)e * R * C;
  unsigned short* dst = outp + (size_t)e * R * C;
  const int tid = threadIdx.x;
  {
    const int lr = tid >> 4, lc = (tid & 15) << 2;
    #pragma unroll
    for (int rr = 0; rr < 4; ++rr){
      const int row = (rr << 4) + lr;
      const float4 v = *(const float4*)(src + (size_t)(r0 + row) * C + c0 + lc);
      tile[row][lc+0] = v.x; tile[row][lc+1] = v.y;
      tile[row][lc+2] = v.z; tile[row][lc+3] = v.w;
    }
  }
  __syncthreads();
  {
    const int wrr = tid >> 3, wcc = (tid & 7) << 3;
    #pragma unroll
    for (int it = 0; it < 2; ++it){
      const int crow = (it << 5) + wrr;
      u16x8 o;
      #pragma unroll
      for (int j = 0; j < 8; ++j) o[j] = f2bf(tile[wcc + j][crow]);
      *(u16x8*)(dst + (size_t)(c0 + crow) * R + r0 + wcc) = o;
    }
  }
}

// ---------------------------------------------------------------------------
// Grouped GEMM, 128x128 tile, BK=64, 4 waves (wave tile 64x64), 2-phase
// double-buffered global_load_lds pipeline (T3 minimum recipe).
// RELU=true : A = xbf gathered via bucket, out = relu->bf16 compact h1.
// RELU=false: A = h1 compact (contiguous), out = prob * acc -> fp32 scatter.
// grid: (NCOLS/128, MAXTILES)
// ---------------------------------------------------------------------------
template<int K, int NCOLS, bool RELU>
__global__ __launch_bounds__(256) void gemm2ph(
    const unsigned short* __restrict__ Ab, const unsigned short* __restrict__ Bt,
    const int* __restrict__ counts, const int* __restrict__ bucket,
    const int* __restrict__ meta, const float* __restrict__ probs,
    unsigned short* __restrict__ h1out, float* __restrict__ fout)
{
  __shared__ unsigned short As[2][BM*64];
  __shared__ unsigned short Bs[2][128*64];
  if ((int)blockIdx.y >= meta[0]) return;
  const int em = meta[16 + blockIdx.y];
  const int e = em >> 16, mt = em & 0xffff;
  const int cnt = counts[e], off_e = meta[1+e];
  const int fbase = blockIdx.x << 7;
  const int tid = threadIdx.x, wave = tid >> 6, lane = tid & 63;
  const int* bkt = bucket + e * NT;
  const int rbase = mt * BM;

  // staging: chunk cw = c*4+wave covers rows [cw*8, cw*8+8); lane>>3 = row-in-chunk
  const int rsub = lane >> 3;
  const int swzb = ((lane & 7) ^ rsub) << 4;   // pre-swizzled source byte col
  const int cm1 = cnt - 1;
  const char* Asrc[4]; const char* Bsrc[4];
  #pragma unroll
  for (int c = 0; c < 4; ++c){
    const int cw = (c << 2) + wave;
    const int row = (cw << 3) + rsub;
    int gr = rbase + row; if (gr > cm1) gr = cm1;
    const size_t arow = RELU ? (size_t)bkt[gr] : (size_t)(off_e + gr);
    Asrc[c] = (const char*)(Ab + arow * K) + swzb;
    Bsrc[c] = (const char*)(Bt + ((size_t)e * NCOLS + fbase + row) * K) + swzb;
  }

  f32x4 acc[4][4] = {};
  const int wr = (wave >> 1) << 6;
  const int wc = (wave & 1) << 6;
  const int lo16 = lane & 15, hi = lane >> 4;
  constexpr int KT = K / 64;

  auto STAGE = [&](int buf, int kt){
    const int kb = kt << 7;                    // 64 bf16 = 128 B per K-step
    #pragma unroll
    for (int c = 0; c < 4; ++c){
      const int cw = (c << 2) + wave;
      gll16(Asrc[c] + kb, (char*)&As[buf][0] + (cw << 10));
      gll16(Bsrc[c] + kb, (char*)&Bs[buf][0] + (cw << 10));
    }
  };
  auto COMPUTE = [&](int buf){
    const char* AsB = (const char*)&As[buf][0];
    const char* BsB = (const char*)&Bs[buf][0];
    #pragma unroll
    for (int kf = 0; kf < 2; ++kf){
      const int ko = (kf << 6) + (hi << 4);
      bf16x8 af[4], bv[4];
      #pragma unroll
      for (int mf = 0; mf < 4; ++mf){
        const int row = wr + (mf << 4) + lo16;
        af[mf] = *(const bf16x8*)(AsB + row * 128 + (ko ^ ((row & 7) << 4)));
      }
      #pragma unroll
      for (int nf = 0; nf < 4; ++nf){
        const int col = wc + (nf << 4) + lo16;
        bv[nf] = *(const bf16x8*)(BsB + col * 128 + (ko ^ ((col & 7) << 4)));
      }
      #pragma unroll
      for (int mf = 0; mf < 4; ++mf)
        #pragma unroll
        for (int nf = 0; nf < 4; ++nf)
          acc[mf][nf] = __builtin_amdgcn_mfma_f32_16x16x32_bf16(af[mf], bv[nf], acc[mf][nf], 0, 0, 0);
    }
  };

  STAGE(0, 0);
  __syncthreads();
  int cur = 0;
  for (int kt = 0; kt < KT - 1; ++kt){
    STAGE(cur ^ 1, kt + 1);    // issue next-tile loads BEFORE compute
    COMPUTE(cur);
    __syncthreads();           // drains vmcnt (next tile ready) + read-done
    cur ^= 1;
  }
  COMPUTE(cur);

  // ---- epilogue ----
  const int rem = cnt - rbase;
  #pragma unroll
  for (int mf = 0; mf < 4; ++mf){
    #pragma unroll
    for (int j = 0; j < 4; ++j){
      const int r = wr + (mf << 4) + (hi << 2) + j;
      if (r < rem){
        if constexpr (RELU){
          const size_t crow = (size_t)(off_e + rbase + r);   // compact row
          #pragma unroll
          for (int nf = 0; nf < 4; ++nf){
            float v = acc[mf][nf][j];
            v = v > 0.f ? v : 0.f;
            h1out[crow * NCOLS + fbase + wc + (nf << 4) + lo16] = f2bf(v);
          }
        } else {
          const int tok = bkt[rbase + r];
          const float p = probs[tok];
          #pragma unroll
          for (int nf = 0; nf < 4; ++nf)
            fout[(size_t)tok * NCOLS + fbase + wc + (nf << 4) + lo16] = p * acc[mf][nf][j];
        }
      }
    }
  }
}

// ---------------------------------------------------------------------------
extern "C" void kernel_launch(void* const* d_in, const int* in_sizes, int n_in,
                              void* d_out, int out_size, void* d_ws, size_t ws_size,
                              hipStream_t stream)
{
  const float* x  = (const float*)d_in[0];   // [2,2048,768]
  const float* wr = (const float*)d_in[1];   // [768,8]
  const float* w1 = (const float*)d_in[2];   // [8,768,3072]
  const float* w2 = (const float*)d_in[3];   // [8,3072,768]
  float* out = (float*)d_out;

  constexpr size_t OUT_L = (size_t)NT * D_;          // router_logits offset
  constexpr size_t OUT_I = OUT_L + (size_t)NT * E_;  // expert_index offset

  char* ws = (char*)d_ws;
  int*            counts = (int*)ws;                              // 32 B
  int*            meta   = (int*)(ws + 256);                      // 224 B
  float*          probs  = (float*)(ws + 1024);                   // 16 KB
  int*            bucket = (int*)(ws + (32u << 10));              // 128 KB
  unsigned short* xbf    = (unsigned short*)(ws + (256u << 10));  // 6 MB
  unsigned short* w1t    = (unsigned short*)(ws + (8ull  << 20)); // 36 MB [E][F][D]
  unsigned short* w2t    = (unsigned short*)(ws + (48ull << 20)); // 36 MB [E][D][F]
  unsigned short* h1c    = (unsigned short*)(ws + (88ull << 20)); // 24 MB compact [NT][F]

  hipMemsetAsync(counts, 0, E_ * sizeof(int), stream);

  router_kernel<<<dim3(NT/4), dim3(256), 0, stream>>>(
      x, wr, out + OUT_L, out + OUT_I, probs, counts, bucket, xbf);

  build_tiles<<<dim3(1), dim3(64), 0, stream>>>(counts, meta);

  transpose_cvt<<<dim3(F_/64, D_/64, E_), dim3(256), 0, stream>>>(w1, w1t, D_, F_);
  transpose_cvt<<<dim3(D_/64, F_/64, E_), dim3(256), 0, stream>>>(w2, w2t, F_, D_);

  gemm2ph<D_, F_, true><<<dim3(F_/128, MAXTILES), dim3(256), 0, stream>>>(
      xbf, w1t, counts, bucket, meta, nullptr, h1c, nullptr);

  gemm2ph<F_, D_, false><<<dim3(D_/128, MAXTILES), dim3(256), 0, stream>>>(
      h1c, w2t, counts, bucket, meta, probs, nullptr, out);
}